// Round 3
// baseline (5027.457 us; speedup 1.0000x reference)
//
#include <hip/hip_runtime.h>
#include <hip/hip_cooperative_groups.h>

namespace cg = cooperative_groups;

typedef __attribute__((ext_vector_type(8))) short short8;
typedef __attribute__((ext_vector_type(4))) float f32x4;

static constexpr int BN    = 512;
static constexpr int ID    = 1024;
static constexpr int HDm   = 2048;
static constexpr int LD    = 1000;
static constexpr int TMAXc = 32;
static constexpr float ALPHAc = 0.05f;

// ---------------- bf16 split helpers (x ~= hi + lo, each bf16) ----------------
__device__ __forceinline__ unsigned short f2bf(float x) {
    unsigned u = __float_as_uint(x);
    u += 0x7fffu + ((u >> 16) & 1u);           // RNE
    return (unsigned short)(u >> 16);
}
__device__ __forceinline__ float bf2f(unsigned short h) {
    return __uint_as_float(((unsigned)h) << 16);
}
__device__ __forceinline__ void split2(float x, unsigned short& hi, unsigned short& lo) {
    hi = f2bf(x);
    lo = f2bf(x - bf2f(hi));
}

// ---------------------------------------------------------------------------
// Split-bf16 MFMA tile: C[BM x 64] = A[BM x K](fp32) @ B[K x 64]
// B given transposed+pre-split: BThi/BTlo rows = output cols, ld = K (=ldb).
// A split to hi/lo on the fly during LDS staging. 3 MFMA terms: ~fp32 accuracy.
// 256 threads, 4 waves; wave w computes cols w*16..w*16+15, all BM rows.
// LDS tiles XOR-swizzled: byte ^= (row&7)<<4  (kills stride-128B bank conflict).
// ---------------------------------------------------------------------------
template<int BM>
__device__ __forceinline__ void mfma_tile(
    const float* __restrict__ A, int lda, int row0,
    const unsigned short* __restrict__ BThi, const unsigned short* __restrict__ BTlo,
    int ldb, int col0, int K, char* lds, f32x4* acc)
{
    constexpr int MF = BM / 16;
    const int t = threadIdx.x, lane = t & 63, wid = t >> 6;
    char* Ah = lds;
    char* Al = lds + BM * 128;
    char* Bh = lds + 2 * BM * 128;
    char* Bl = lds + 2 * BM * 128 + 8192;
#pragma unroll
    for (int m = 0; m < MF; ++m) { f32x4 z = {0.f, 0.f, 0.f, 0.f}; acc[m] = z; }

    constexpr int EPT = BM / 4;        // floats of A per thread (16 or 8)
    constexpr int TPR = 64 / EPT;      // threads per A row (4 or 8)
    const int ar = t / TPR;
    const int ac = (t % TPR) * EPT;
    const int br = t >> 2;             // B tile: 64 rows, 4 threads/row
    const int bc = (t & 3) * 16;

    const float* Aptr = A + (size_t)(row0 + ar) * lda + ac;
    const unsigned short* Bhp = BThi + (size_t)(col0 + br) * ldb + bc;
    const unsigned short* Blp = BTlo + (size_t)(col0 + br) * ldb + bc;

    for (int k0 = 0; k0 < K; k0 += 64) {
        __syncthreads();               // prior reads of LDS done
        // ---- stage A (fp32 -> hi/lo bf16) ----
#pragma unroll
        for (int g = 0; g < EPT / 4; ++g) {
            float4 v = *(const float4*)(Aptr + k0 + 4 * g);
            unsigned short h0, h1, h2, h3, l0, l1, l2, l3;
            split2(v.x, h0, l0); split2(v.y, h1, l1);
            split2(v.z, h2, l2); split2(v.w, h3, l3);
            uint2 hp = make_uint2((unsigned)h0 | ((unsigned)h1 << 16),
                                  (unsigned)h2 | ((unsigned)h3 << 16));
            uint2 lp = make_uint2((unsigned)l0 | ((unsigned)l1 << 16),
                                  (unsigned)l2 | ((unsigned)l3 << 16));
            const int byte = ar * 128 + (ac + 4 * g) * 2;
            const int sb = byte ^ ((ar & 7) << 4);
            *(uint2*)(Ah + sb) = hp;
            *(uint2*)(Al + sb) = lp;
        }
        // ---- stage B (pre-split bf16, 32B per thread from hi and lo) ----
        {
            const int byte = br * 128 + bc * 2;          // bits 0..4 zero
            const int sb = byte ^ ((br & 7) << 4);
            const uint4* gh = (const uint4*)(Bhp + k0);
            const uint4* gl = (const uint4*)(Blp + k0);
            *(uint4*)(Bh + sb) = gh[0];
            *(uint4*)(Bh + (sb ^ 16)) = gh[1];
            *(uint4*)(Bl + sb) = gl[0];
            *(uint4*)(Bl + (sb ^ 16)) = gl[1];
        }
        __syncthreads();
        // ---- MFMA ----
        const int colr = wid * 16 + (lane & 15);
        const int kb0 = (lane >> 4) * 8;
#pragma unroll
        for (int ks = 0; ks < 2; ++ks) {
            const int kb = (ks * 32 + kb0) * 2;
            const int bbyte = (colr * 128 + kb) ^ ((colr & 7) << 4);
            short8 bh = *(const short8*)(Bh + bbyte);
            short8 bl = *(const short8*)(Bl + bbyte);
#pragma unroll
            for (int m = 0; m < MF; ++m) {
                const int arow = m * 16 + (lane & 15);
                const int abyte = (arow * 128 + kb) ^ ((arow & 7) << 4);
                short8 ah = *(const short8*)(Ah + abyte);
                short8 al = *(const short8*)(Al + abyte);
                acc[m] = __builtin_amdgcn_mfma_f32_16x16x32_bf16(ah, bh, acc[m], 0, 0, 0);
                acc[m] = __builtin_amdgcn_mfma_f32_16x16x32_bf16(al, bh, acc[m], 0, 0, 0);
                acc[m] = __builtin_amdgcn_mfma_f32_16x16x32_bf16(ah, bl, acc[m], 0, 0, 0);
            }
        }
    }
}

// ---------------------------------------------------------------------------
// Prep kernels
// ---------------------------------------------------------------------------
__global__ void k_init(int* active, int* nact, float* scal)
{
    int i = blockIdx.x * blockDim.x + threadIdx.x;
    if (i < BN) active[i] = 1;
    if (i < TMAXc + 1) nact[i] = 0;
    if (i < 8) scal[i] = 0.f;
}

// max column L1 of RH*MH -> atomicMax scal[0]   (32 blocks x 1024 thr)
__global__ __launch_bounds__(1024) void k_colsum_wh(const float* __restrict__ RH,
                                                    const float* __restrict__ MH,
                                                    float* scal)
{
    const int col = blockIdx.x * 64 + (threadIdx.x & 63);
    const int rs  = threadIdx.x >> 6;    // 0..15
    float s = 0.f;
    for (int i = rs; i < HDm; i += 16)
        s += fabsf(RH[(size_t)i * HDm + col] * MH[(size_t)i * HDm + col]);
    __shared__ float red[16][64];
    red[rs][threadIdx.x & 63] = s;
    __syncthreads();
    if (threadIdx.x < 64) {
        float c = 0.f;
#pragma unroll
        for (int j = 0; j < 16; ++j) c += red[j][threadIdx.x];
#pragma unroll
        for (int off = 1; off < 64; off <<= 1) c = fmaxf(c, __shfl_xor(c, off));
        if (threadIdx.x == 0)
            atomicMax((unsigned int*)&scal[0], __float_as_uint(c));
    }
}

// max column L1 of RHL*MHL -> atomicMax scal[1]   (16 blocks x 1024 thr)
__global__ __launch_bounds__(1024) void k_colsum_whl(const float* __restrict__ RHL,
                                                     const float* __restrict__ MHL,
                                                     float* scal)
{
    const int col = blockIdx.x * 64 + (threadIdx.x & 63);
    const int rs  = threadIdx.x >> 6;
    float s = 0.f;
    if (col < LD) {
        for (int i = rs; i < HDm; i += 16)
            s += fabsf(RHL[(size_t)i * LD + col] * MHL[(size_t)i * LD + col]);
    }
    __shared__ float red[16][64];
    red[rs][threadIdx.x & 63] = s;
    __syncthreads();
    if (threadIdx.x < 64) {
        float c = 0.f;
#pragma unroll
        for (int j = 0; j < 16; ++j) c += red[j][threadIdx.x];
#pragma unroll
        for (int off = 1; off < 64; off <<= 1) c = fmaxf(c, __shfl_xor(c, off));
        if (threadIdx.x == 0)
            atomicMax((unsigned int*)&scal[1], __float_as_uint(c));
    }
}

__global__ void k_scalars(float* scal)
{
    if (threadIdx.x == 0 && blockIdx.x == 0) {
        scal[2] = 0.95f / fmaxf(scal[0], 1e-8f);   // W_H scale
        scal[3] = scal[1] * 19.f;                  // gamma_coef = whl_inf * rho/(1-rho)
    }
}

// Transposed split:  O{hi,lo}[c][r] = split(R[r][c] * M[r][c] * s), c >= NC -> 0.
// Input R,M: [NR][NC] row-major. Output: [NCp][NR] row-major. 64x64 LDS transpose.
__global__ __launch_bounds__(256) void k_wsplit(
    const float* __restrict__ R, const float* __restrict__ M,
    unsigned short* __restrict__ Ohi, unsigned short* __restrict__ Olo,
    int NR, int NC, int NCp, const float* __restrict__ scal, int scidx)
{
    __shared__ float T[64][65];
    const int nct = NCp >> 6;
    const int c0 = (blockIdx.x % nct) << 6;
    const int r0 = (blockIdx.x / nct) << 6;
    const float s = (scidx >= 0) ? scal[scidx] : 1.f;
    const int t = threadIdx.x;
    const int ir = t >> 2, ics = (t & 3) << 4;
#pragma unroll
    for (int i = 0; i < 16; ++i) {
        const int c = c0 + ics + i;
        float v = 0.f;
        if (c < NC) {
            const size_t idx = (size_t)(r0 + ir) * NC + c;
            v = R[idx] * M[idx] * s;
        }
        T[ir][ics + i] = v;
    }
    __syncthreads();
    const int oc = t >> 2, ors = (t & 3) << 4;
    unsigned short hb[16], lb[16];
#pragma unroll
    for (int i = 0; i < 16; ++i) split2(T[ors + i][oc], hb[i], lb[i]);
    const size_t base = (size_t)(c0 + oc) * NR + r0 + ors;
    uint4 v;
    v.x = hb[0] | ((unsigned)hb[1] << 16);  v.y = hb[2] | ((unsigned)hb[3] << 16);
    v.z = hb[4] | ((unsigned)hb[5] << 16);  v.w = hb[6] | ((unsigned)hb[7] << 16);
    *(uint4*)(Ohi + base) = v;
    v.x = hb[8] | ((unsigned)hb[9] << 16);  v.y = hb[10] | ((unsigned)hb[11] << 16);
    v.z = hb[12] | ((unsigned)hb[13] << 16); v.w = hb[14] | ((unsigned)hb[15] << 16);
    *(uint4*)(Ohi + base + 8) = v;
    v.x = lb[0] | ((unsigned)lb[1] << 16);  v.y = lb[2] | ((unsigned)lb[3] << 16);
    v.z = lb[4] | ((unsigned)lb[5] << 16);  v.w = lb[6] | ((unsigned)lb[7] << 16);
    *(uint4*)(Olo + base) = v;
    v.x = lb[8] | ((unsigned)lb[9] << 16);  v.y = lb[10] | ((unsigned)lb[11] << 16);
    v.z = lb[12] | ((unsigned)lb[13] << 16); v.w = lb[14] | ((unsigned)lb[15] << 16);
    *(uint4*)(Olo + base + 8) = v;
}

// drive = x @ W_IH + BH   (MFMA, 256 blocks: 8 M-tiles x 32 N-tiles of 64x64)
__global__ __launch_bounds__(256) void k_drive_mfma(
    const float* __restrict__ x,
    const unsigned short* __restrict__ WIHThi, const unsigned short* __restrict__ WIHTlo,
    const float* __restrict__ BH, float* __restrict__ drive)
{
    __shared__ char lds[32768];
    f32x4 acc[4];
    const int m = blockIdx.x >> 5, n = blockIdx.x & 31;
    const int row0 = m * 64, col0 = n * 64;
    mfma_tile<64>(x, ID, row0, WIHThi, WIHTlo, ID, col0, ID, lds, acc);
    const int lane = threadIdx.x & 63, wid = threadIdx.x >> 6;
    const int gc = col0 + wid * 16 + (lane & 15);
    const float bh = BH[gc];
#pragma unroll
    for (int mm = 0; mm < 4; ++mm) {
        const int gr0 = row0 + mm * 16 + ((lane >> 4) << 2);
#pragma unroll
        for (int r = 0; r < 4; ++r)
            drive[(size_t)(gr0 + r) * HDm + gc] = acc[mm][r] + bh;
    }
}

// ---------------------------------------------------------------------------
// Cooperative loop kernel
// ---------------------------------------------------------------------------
__global__ __launch_bounds__(256) void k_crp_loop(
    const unsigned short* __restrict__ WHThi, const unsigned short* __restrict__ WHTlo,
    const unsigned short* __restrict__ WHLThi, const unsigned short* __restrict__ WHLTlo,
    const float* __restrict__ drive, const float* __restrict__ BL,
    float* Ha, float* Hb, float* logits,
    int* active, int* nact, const float* scal, float* out)
{
    cg::grid_group grid = cg::this_grid();
    __shared__ char lds[32768];
    __shared__ int s_any;
    const int nb = gridDim.x, bid = blockIdx.x, tid = threadIdx.x;
    const float gamma2 = 2.f * scal[3];
    float* Hs = Ha;
    float* Hn = Hb;

    for (int t = 1; t <= TMAXc; ++t) {
        // ---- P1: Hn = select(active, LeakyReLU(Hs@W_H + drive), Hs) ----
        {
            const int m = bid >> 5, n = bid & 31;
            const int row0 = m * 64, col0 = n * 64;
            if (tid < 64) {
                int a = ((const volatile int*)active)[row0 + tid];
                unsigned long long bl = __ballot(a != 0);
                if (tid == 0) s_any = (bl != 0ull);
            }
            __syncthreads();
            if (s_any) {
                f32x4 acc[4];
                mfma_tile<64>(Hs, HDm, row0, WHThi, WHTlo, HDm, col0, HDm, lds, acc);
                const int lane = tid & 63, wid = tid >> 6;
                const int gc = col0 + wid * 16 + (lane & 15);
#pragma unroll
                for (int mm = 0; mm < 4; ++mm) {
                    const int gr0 = row0 + mm * 16 + ((lane >> 4) << 2);
#pragma unroll
                    for (int r = 0; r < 4; ++r) {
                        const int gr = gr0 + r;
                        const float pre = acc[mm][r] + drive[(size_t)gr * HDm + gc];
                        const float av = pre >= 0.f ? pre : ALPHAc * pre;
                        const int act = ((const volatile int*)active)[gr];
                        Hn[(size_t)gr * HDm + gc] = act ? av : Hs[(size_t)gr * HDm + gc];
                    }
                }
            } else if (n == 0) {       // whole row-tile frozen: one block copies
                const float4* src = (const float4*)(Hs + (size_t)row0 * HDm);
                float4* dst = (float4*)(Hn + (size_t)row0 * HDm);
                for (int i = tid; i < 64 * HDm / 4; i += 256) dst[i] = src[i];
            }
        }
        grid.sync();

        // ---- P2: logits = Hn @ W_HL + BL  (skip fully-frozen row-tiles) ----
        {
            const int m = bid >> 4, n = bid & 15;
            const int row0 = m * 32, col0 = n * 64;
            __syncthreads();
            if (tid < 64) {
                int a = (tid < 32) ? ((const volatile int*)active)[row0 + tid] : 0;
                unsigned long long bl = __ballot(a != 0);
                if (tid == 0) s_any = (bl != 0ull);
            }
            __syncthreads();
            if (s_any) {
                f32x4 acc[2];
                mfma_tile<32>(Hn, HDm, row0, WHLThi, WHLTlo, HDm, col0, HDm, lds, acc);
                const int lane = tid & 63, wid = tid >> 6;
                const int gc = col0 + wid * 16 + (lane & 15);
                if (gc < LD) {
                    const float blv = BL[gc];
#pragma unroll
                    for (int mm = 0; mm < 2; ++mm) {
                        const int gr0 = row0 + mm * 16 + ((lane >> 4) << 2);
#pragma unroll
                        for (int r = 0; r < 4; ++r)
                            logits[(size_t)(gr0 + r) * LD + gc] = acc[mm][r] + blv;
                    }
                }
            }
        }
        grid.sync();

        // ---- P3: per-row certification (one wave per row) ----
        {
            const int lane = tid & 63;
            const int wave = (bid * 256 + tid) >> 6;
            const int nwaves = nb * 4;
            for (int b = wave; b < BN; b += nwaves) {
                if (!((const volatile int*)active)[b]) continue;
                const float* hn = Hn + (size_t)b * HDm;
                const float* hs = Hs + (size_t)b * HDm;
                float dh = 0.f;
                for (int h = lane; h < HDm; h += 64)
                    dh = fmaxf(dh, fabsf(hn[h] - hs[h]));
#pragma unroll
                for (int off = 1; off < 64; off <<= 1)
                    dh = fmaxf(dh, __shfl_xor(dh, off));
                const float* lr = logits + (size_t)b * LD;
                float m1 = -3.4e38f, m2 = -3.4e38f;
                for (int j = lane; j < LD; j += 64) {
                    float v = lr[j];
                    if (v > m1) { m2 = m1; m1 = v; }
                    else m2 = fmaxf(m2, v);
                }
#pragma unroll
                for (int off = 1; off < 64; off <<= 1) {
                    float o1 = __shfl_xor(m1, off);
                    float o2 = __shfl_xor(m2, off);
                    if (o1 > m1) { m2 = fmaxf(m1, o2); m1 = o1; }
                    else m2 = fmaxf(m2, o1);
                }
                const bool newly = (m1 - m2) > gamma2 * dh;
                if (newly) {
                    for (int j = lane; j < LD; j += 64) out[(size_t)b * LD + j] = lr[j];
                    if (lane == 0) active[b] = 0;
                } else if (lane == 0) {
                    atomicAdd(&nact[t], 1);
                }
            }
        }
        grid.sync();
        const int remaining = ((const volatile int*)nact)[t];
        float* tmp = Hs; Hs = Hn; Hn = tmp;
        if (remaining == 0) break;
    }

    // ---- never-certified rows take last logits ----
    {
        const int lane = tid & 63;
        const int wave = (bid * 256 + tid) >> 6;
        const int nwaves = nb * 4;
        for (int b = wave; b < BN; b += nwaves) {
            if (!((const volatile int*)active)[b]) continue;
            const float* lr = logits + (size_t)b * LD;
            for (int j = lane; j < LD; j += 64) out[(size_t)b * LD + j] = lr[j];
        }
    }
}

// ---------------------------------------------------------------------------
extern "C" void kernel_launch(void* const* d_in, const int* in_sizes, int n_in,
                              void* d_out, int out_size, void* d_ws, size_t ws_size,
                              hipStream_t stream)
{
    const float* x   = (const float*)d_in[0];
    const float* RIH = (const float*)d_in[1];
    const float* RH  = (const float*)d_in[2];
    const float* RHL = (const float*)d_in[3];
    const float* BH  = (const float*)d_in[4];
    const float* BL  = (const float*)d_in[5];
    const float* MIH = (const float*)d_in[6];
    const float* MH  = (const float*)d_in[7];
    const float* MHL = (const float*)d_in[8];
    float* out = (float*)d_out;
    char* w = (char*)d_ws;

    // workspace layout (39.8 MB; WX region shared by W_IH^T then W_HL^T)
    unsigned short* WHThi = (unsigned short*)(w);                 //  8 MB
    unsigned short* WHTlo = (unsigned short*)(w + 8388608);       //  8 MB
    unsigned short* WXhi  = (unsigned short*)(w + 16777216);      //  4 MB
    unsigned short* WXlo  = (unsigned short*)(w + 20971520);      //  4 MB
    float* drive  = (float*)(w + 25165824);                       //  4 MB
    float* Ha     = (float*)(w + 29360128);                       //  4 MB
    float* Hb     = (float*)(w + 33554432);                       //  4 MB
    float* logits = (float*)(w + 37748736);                       //  2 MB
    float* scal   = (float*)(w + 39796736);
    int*   active = (int*)(w + 39796768);
    int*   nact   = (int*)(w + 39798816);

    k_init<<<2, 256, 0, stream>>>(active, nact, scal);
    k_colsum_wh<<<32, 1024, 0, stream>>>(RH, MH, scal);
    k_colsum_whl<<<16, 1024, 0, stream>>>(RHL, MHL, scal);
    k_scalars<<<1, 64, 0, stream>>>(scal);
    // W_IH^T split -> WX, then drive (uses it), then overwrite WX with W_HL^T
    k_wsplit<<<512, 256, 0, stream>>>(RIH, MIH, WXhi, WXlo, ID, HDm, HDm, scal, -1);
    k_drive_mfma<<<256, 256, 0, stream>>>(x, WXhi, WXlo, BH, drive);
    k_wsplit<<<1024, 256, 0, stream>>>(RH, MH, WHThi, WHTlo, HDm, HDm, HDm, scal, 2);
    k_wsplit<<<512, 256, 0, stream>>>(RHL, MHL, WXhi, WXlo, HDm, LD, 1024, scal, -1);
    hipMemsetAsync(Ha, 0, (size_t)BN * HDm * sizeof(float), stream);

    void* args[] = {(void*)&WHThi, (void*)&WHTlo, (void*)&WXhi, (void*)&WXlo,
                    (void*)&drive, (void*)&BL, (void*)&Ha, (void*)&Hb, (void*)&logits,
                    (void*)&active, (void*)&nact, (void*)&scal, (void*)&out};
    hipLaunchCooperativeKernel(reinterpret_cast<void*>(k_crp_loop),
                               dim3(256), dim3(256), args, 0, stream);
}

// Round 4
// 4176.412 us; speedup vs baseline: 1.2038x; 1.2038x over previous
//
#include <hip/hip_runtime.h>
#include <hip/hip_cooperative_groups.h>

namespace cg = cooperative_groups;

typedef __attribute__((ext_vector_type(8))) short short8;
typedef __attribute__((ext_vector_type(4))) float f32x4;

static constexpr int BN    = 512;
static constexpr int ID    = 1024;
static constexpr int HDm   = 2048;
static constexpr int LD    = 1000;
static constexpr int TMAXc = 32;
static constexpr float ALPHAc = 0.05f;

// ---------------- bf16 split helpers (x ~= hi + lo, each bf16) ----------------
__device__ __forceinline__ unsigned short f2bf(float x) {
    unsigned u = __float_as_uint(x);
    u += 0x7fffu + ((u >> 16) & 1u);           // RNE
    return (unsigned short)(u >> 16);
}
__device__ __forceinline__ float bf2f(unsigned short h) {
    return __uint_as_float(((unsigned)h) << 16);
}
__device__ __forceinline__ void split2(float x, unsigned short& hi, unsigned short& lo) {
    hi = f2bf(x);
    lo = f2bf(x - bf2f(hi));
}

// ---------------------------------------------------------------------------
// 64x64 tile, 1024 threads (16 waves, each one 16x16 C-fragment), K-step 64,
// register-prefetched staging, split-bf16 3-term MFMA (~fp32 accuracy).
// A fp32 [M,K] row-major; B transposed pre-split bf16 [N,K] (rows = out cols).
// LDS XOR swizzle: byte ^= (row&7)<<4.
// ---------------------------------------------------------------------------
__device__ __forceinline__ void tile64_gemm(
    const float* __restrict__ A, int lda, int row0,
    const unsigned short* __restrict__ BThi, const unsigned short* __restrict__ BTlo,
    int ldk, int col0, int K, char* lds, f32x4& acc)
{
    char* Ah = lds;
    char* Al = lds + 8192;
    char* Bh = lds + 16384;
    char* Bl = lds + 24576;
    const int t = threadIdx.x, lane = t & 63, w = t >> 6;
    const int wrow = w >> 2, wcol = w & 3;
    f32x4 z = {0.f, 0.f, 0.f, 0.f};
    acc = z;

    const int ar = t >> 4, ac = (t & 15) << 2;     // A: 64 rows x 64, float4/thread
    const int br = t >> 4, bc = (t & 15) << 2;     // B: 64 rows x 64, uint2/thread
    const float* Ap = A + (size_t)(row0 + ar) * lda + ac;
    const unsigned short* Bhp = BThi + (size_t)(col0 + br) * ldk + bc;
    const unsigned short* Blp = BTlo + (size_t)(col0 + br) * ldk + bc;
    const int asb = (ar * 128 + ac * 2) ^ ((ar & 7) << 4);
    const int bsb = (br * 128 + bc * 2) ^ ((br & 7) << 4);
    const int colr = wcol * 16 + (lane & 15);
    const int arow = wrow * 16 + (lane & 15);
    const int bb0 = colr * 128, ab0 = arow * 128;
    const int bxor = (colr & 7) << 4, axor = (arow & 7) << 4;
    const int kb0 = (lane >> 4) << 4;              // byte offset of 8-elem k-group

    float4 av = *(const float4*)Ap;                // prefetch k0=0
    uint2 bhv = *(const uint2*)Bhp;
    uint2 blv = *(const uint2*)Blp;

    for (int k0 = 0; k0 < K; k0 += 64) {
        unsigned short h0, h1, h2, h3, l0, l1, l2, l3;
        split2(av.x, h0, l0); split2(av.y, h1, l1);
        split2(av.z, h2, l2); split2(av.w, h3, l3);
        uint2 ahp = make_uint2((unsigned)h0 | ((unsigned)h1 << 16),
                               (unsigned)h2 | ((unsigned)h3 << 16));
        uint2 alp = make_uint2((unsigned)l0 | ((unsigned)l1 << 16),
                               (unsigned)l2 | ((unsigned)l3 << 16));
        __syncthreads();                            // prior LDS readers done
        *(uint2*)(Ah + asb) = ahp;
        *(uint2*)(Al + asb) = alp;
        *(uint2*)(Bh + bsb) = bhv;
        *(uint2*)(Bl + bsb) = blv;
        if (k0 + 64 < K) {                          // prefetch next chunk (hides latency under MFMA)
            av  = *(const float4*)(Ap + k0 + 64);
            bhv = *(const uint2*)(Bhp + k0 + 64);
            blv = *(const uint2*)(Blp + k0 + 64);
        }
        __syncthreads();
#pragma unroll
        for (int ks = 0; ks < 2; ++ks) {
            const int kb = ks * 64 + kb0;
            short8 bh = *(const short8*)(Bh + ((bb0 + kb) ^ bxor));
            short8 bl = *(const short8*)(Bl + ((bb0 + kb) ^ bxor));
            short8 ah = *(const short8*)(Ah + ((ab0 + kb) ^ axor));
            short8 al = *(const short8*)(Al + ((ab0 + kb) ^ axor));
            acc = __builtin_amdgcn_mfma_f32_16x16x32_bf16(ah, bh, acc, 0, 0, 0);
            acc = __builtin_amdgcn_mfma_f32_16x16x32_bf16(al, bh, acc, 0, 0, 0);
            acc = __builtin_amdgcn_mfma_f32_16x16x32_bf16(ah, bl, acc, 0, 0, 0);
        }
    }
}

// ---------------------------------------------------------------------------
// 32x64 tile, K=2048, 1024 threads; 16 waves = 8 C-fragments x 2 K-halves
// (wave s -> even 64-chunks, wave s+8 -> odd 64-chunks), 128-wide K staging.
// Deterministic LDS reduction pairs the halves. LDS swizzle: ^ (row&15)<<4.
// ---------------------------------------------------------------------------
__device__ __forceinline__ void tile32_gemm_ks(
    const float* __restrict__ A, int row0,
    const unsigned short* __restrict__ BThi, const unsigned short* __restrict__ BTlo,
    int col0, char* lds, f32x4& acc, int& s_out, int& p_out)
{
    char* Ah = lds;                  // 32*256   = 8 KB
    char* Al = lds + 8192;           //            8 KB
    char* Bh = lds + 16384;          // 64*256   = 16 KB
    char* Bl = lds + 32768;          //            16 KB
    const int t = threadIdx.x, lane = t & 63, w = t >> 6;
    const int s = w & 7, p = w >> 3;
    s_out = s; p_out = p;
    const int mrow = s >> 2, wcol = s & 3;
    f32x4 z = {0.f, 0.f, 0.f, 0.f};
    acc = z;

    const int ar = t >> 5, ac = (t & 31) << 2;     // A: 32 rows x 128, float4/thread
    const int br = t >> 4, bc = (t & 15) << 3;     // B: 64 rows x 128, uint4/thread
    const float* Ap = A + (size_t)(row0 + ar) * HDm + ac;
    const unsigned short* Bhp = BThi + (size_t)(col0 + br) * HDm + bc;
    const unsigned short* Blp = BTlo + (size_t)(col0 + br) * HDm + bc;
    const int asb = (ar * 256 + ac * 2) ^ ((ar & 15) << 4);
    const int bsb = (br * 256 + bc * 2) ^ ((br & 15) << 4);
    const int colr = wcol * 16 + (lane & 15);
    const int arow = mrow * 16 + (lane & 15);
    const int bb0 = colr * 256, ab0 = arow * 256;
    const int bxor = (colr & 15) << 4, axor = (arow & 15) << 4;
    const int kc = p * 128;                         // byte offset of this wave's K-half
    const int kb0 = (lane >> 4) << 4;

    float4 av = *(const float4*)Ap;
    uint4 bhv = *(const uint4*)Bhp;
    uint4 blv = *(const uint4*)Blp;

    for (int k0 = 0; k0 < HDm; k0 += 128) {
        unsigned short h0, h1, h2, h3, l0, l1, l2, l3;
        split2(av.x, h0, l0); split2(av.y, h1, l1);
        split2(av.z, h2, l2); split2(av.w, h3, l3);
        uint2 ahp = make_uint2((unsigned)h0 | ((unsigned)h1 << 16),
                               (unsigned)h2 | ((unsigned)h3 << 16));
        uint2 alp = make_uint2((unsigned)l0 | ((unsigned)l1 << 16),
                               (unsigned)l2 | ((unsigned)l3 << 16));
        __syncthreads();
        *(uint2*)(Ah + asb) = ahp;
        *(uint2*)(Al + asb) = alp;
        *(uint4*)(Bh + bsb) = bhv;
        *(uint4*)(Bl + bsb) = blv;
        if (k0 + 128 < HDm) {
            av  = *(const float4*)(Ap + k0 + 128);
            bhv = *(const uint4*)(Bhp + k0 + 128);
            blv = *(const uint4*)(Blp + k0 + 128);
        }
        __syncthreads();
#pragma unroll
        for (int ks = 0; ks < 2; ++ks) {
            const int kb = kc + ks * 64 + kb0;
            short8 bh = *(const short8*)(Bh + ((bb0 + kb) ^ bxor));
            short8 bl = *(const short8*)(Bl + ((bb0 + kb) ^ bxor));
            short8 ah = *(const short8*)(Ah + ((ab0 + kb) ^ axor));
            short8 al = *(const short8*)(Al + ((ab0 + kb) ^ axor));
            acc = __builtin_amdgcn_mfma_f32_16x16x32_bf16(ah, bh, acc, 0, 0, 0);
            acc = __builtin_amdgcn_mfma_f32_16x16x32_bf16(al, bh, acc, 0, 0, 0);
            acc = __builtin_amdgcn_mfma_f32_16x16x32_bf16(ah, bl, acc, 0, 0, 0);
        }
    }
}

// ---------------------------------------------------------------------------
// Prep kernels
// ---------------------------------------------------------------------------
__global__ void k_init(int* active, int* nact, float* scal)
{
    int i = blockIdx.x * blockDim.x + threadIdx.x;
    if (i < BN) active[i] = 1;
    if (i < TMAXc + 1) nact[i] = 0;
    if (i < 8) scal[i] = 0.f;
}

__global__ __launch_bounds__(1024) void k_colsum_wh(const float* __restrict__ RH,
                                                    const float* __restrict__ MH,
                                                    float* scal)
{
    const int col = blockIdx.x * 64 + (threadIdx.x & 63);
    const int rs  = threadIdx.x >> 6;
    float s = 0.f;
    for (int i = rs; i < HDm; i += 16)
        s += fabsf(RH[(size_t)i * HDm + col] * MH[(size_t)i * HDm + col]);
    __shared__ float red[16][64];
    red[rs][threadIdx.x & 63] = s;
    __syncthreads();
    if (threadIdx.x < 64) {
        float c = 0.f;
#pragma unroll
        for (int j = 0; j < 16; ++j) c += red[j][threadIdx.x];
#pragma unroll
        for (int off = 1; off < 64; off <<= 1) c = fmaxf(c, __shfl_xor(c, off));
        if (threadIdx.x == 0)
            atomicMax((unsigned int*)&scal[0], __float_as_uint(c));
    }
}

__global__ __launch_bounds__(1024) void k_colsum_whl(const float* __restrict__ RHL,
                                                     const float* __restrict__ MHL,
                                                     float* scal)
{
    const int col = blockIdx.x * 64 + (threadIdx.x & 63);
    const int rs  = threadIdx.x >> 6;
    float s = 0.f;
    if (col < LD) {
        for (int i = rs; i < HDm; i += 16)
            s += fabsf(RHL[(size_t)i * LD + col] * MHL[(size_t)i * LD + col]);
    }
    __shared__ float red[16][64];
    red[rs][threadIdx.x & 63] = s;
    __syncthreads();
    if (threadIdx.x < 64) {
        float c = 0.f;
#pragma unroll
        for (int j = 0; j < 16; ++j) c += red[j][threadIdx.x];
#pragma unroll
        for (int off = 1; off < 64; off <<= 1) c = fmaxf(c, __shfl_xor(c, off));
        if (threadIdx.x == 0)
            atomicMax((unsigned int*)&scal[1], __float_as_uint(c));
    }
}

__global__ void k_scalars(float* scal)
{
    if (threadIdx.x == 0 && blockIdx.x == 0) {
        scal[2] = 0.95f / fmaxf(scal[0], 1e-8f);   // W_H scale
        scal[3] = scal[1] * 19.f;                  // gamma_coef
    }
}

// Transposed split:  O{hi,lo}[c][r] = split(R[r][c] * M[r][c] * s)
__global__ __launch_bounds__(256) void k_wsplit(
    const float* __restrict__ R, const float* __restrict__ M,
    unsigned short* __restrict__ Ohi, unsigned short* __restrict__ Olo,
    int NR, int NC, int NCp, const float* __restrict__ scal, int scidx)
{
    __shared__ float T[64][65];
    const int nct = NCp >> 6;
    const int c0 = (blockIdx.x % nct) << 6;
    const int r0 = (blockIdx.x / nct) << 6;
    const float s = (scidx >= 0) ? scal[scidx] : 1.f;
    const int t = threadIdx.x;
    const int ir = t >> 2, ics = (t & 3) << 4;
#pragma unroll
    for (int i = 0; i < 16; ++i) {
        const int c = c0 + ics + i;
        float v = 0.f;
        if (c < NC) {
            const size_t idx = (size_t)(r0 + ir) * NC + c;
            v = R[idx] * M[idx] * s;
        }
        T[ir][ics + i] = v;
    }
    __syncthreads();
    const int oc = t >> 2, ors = (t & 3) << 4;
    unsigned short hb[16], lb[16];
#pragma unroll
    for (int i = 0; i < 16; ++i) split2(T[ors + i][oc], hb[i], lb[i]);
    const size_t base = (size_t)(c0 + oc) * NR + r0 + ors;
    uint4 v;
    v.x = hb[0] | ((unsigned)hb[1] << 16);  v.y = hb[2] | ((unsigned)hb[3] << 16);
    v.z = hb[4] | ((unsigned)hb[5] << 16);  v.w = hb[6] | ((unsigned)hb[7] << 16);
    *(uint4*)(Ohi + base) = v;
    v.x = hb[8] | ((unsigned)hb[9] << 16);  v.y = hb[10] | ((unsigned)hb[11] << 16);
    v.z = hb[12] | ((unsigned)hb[13] << 16); v.w = hb[14] | ((unsigned)hb[15] << 16);
    *(uint4*)(Ohi + base + 8) = v;
    v.x = lb[0] | ((unsigned)lb[1] << 16);  v.y = lb[2] | ((unsigned)lb[3] << 16);
    v.z = lb[4] | ((unsigned)lb[5] << 16);  v.w = lb[6] | ((unsigned)lb[7] << 16);
    *(uint4*)(Olo + base) = v;
    v.x = lb[8] | ((unsigned)lb[9] << 16);  v.y = lb[10] | ((unsigned)lb[11] << 16);
    v.z = lb[12] | ((unsigned)lb[13] << 16); v.w = lb[14] | ((unsigned)lb[15] << 16);
    *(uint4*)(Olo + base + 8) = v;
}

// drive = x @ W_IH + BH
__global__ __launch_bounds__(1024) void k_drive_mfma(
    const float* __restrict__ x,
    const unsigned short* __restrict__ WIHThi, const unsigned short* __restrict__ WIHTlo,
    const float* __restrict__ BH, float* __restrict__ drive)
{
    __shared__ char lds[32768];
    f32x4 acc;
    const int row0 = (blockIdx.x >> 5) * 64, col0 = (blockIdx.x & 31) * 64;
    tile64_gemm(x, ID, row0, WIHThi, WIHTlo, ID, col0, ID, lds, acc);
    const int lane = threadIdx.x & 63, w = threadIdx.x >> 6;
    const int gc = col0 + (w & 3) * 16 + (lane & 15);
    const int gr0 = row0 + (w >> 2) * 16 + ((lane >> 4) << 2);
    const float bh = BH[gc];
#pragma unroll
    for (int r = 0; r < 4; ++r)
        drive[(size_t)(gr0 + r) * HDm + gc] = acc[r] + bh;
}

// ---------------------------------------------------------------------------
// Cooperative loop kernel: 256 blocks x 1024 threads
// ---------------------------------------------------------------------------
__global__ __launch_bounds__(1024) void k_crp_loop(
    const unsigned short* __restrict__ WHThi, const unsigned short* __restrict__ WHTlo,
    const unsigned short* __restrict__ WHLThi, const unsigned short* __restrict__ WHLTlo,
    const float* __restrict__ drive, const float* __restrict__ BL,
    float* Ha, float* Hb, float* logits,
    int* active, int* nact, const float* scal, float* out)
{
    cg::grid_group grid = cg::this_grid();
    __shared__ char lds[49152];
    __shared__ int s_any;
    const int bid = blockIdx.x, tid = threadIdx.x;
    const float gamma2 = 2.f * scal[3];
    float* Hs = Ha;
    float* Hn = Hb;

    for (int t = 1; t <= TMAXc; ++t) {
        // ---- P1: Hn = select(active, LeakyReLU(Hs@W_H + drive), Hs) ----
        {
            const int row0 = (bid >> 5) * 64, col0 = (bid & 31) * 64;
            if (tid < 64) {
                int a = ((const volatile int*)active)[row0 + tid];
                unsigned long long bl = __ballot(a != 0);
                if (tid == 0) s_any = (bl != 0ull);
            }
            __syncthreads();
            if (s_any) {
                f32x4 acc;
                tile64_gemm(Hs, HDm, row0, WHThi, WHTlo, HDm, col0, HDm, lds, acc);
                const int lane = tid & 63, w = tid >> 6;
                const int gc = col0 + (w & 3) * 16 + (lane & 15);
                const int gr0 = row0 + (w >> 2) * 16 + ((lane >> 4) << 2);
#pragma unroll
                for (int r = 0; r < 4; ++r) {
                    const int gr = gr0 + r;
                    const float pre = acc[r] + drive[(size_t)gr * HDm + gc];
                    const float av = pre >= 0.f ? pre : ALPHAc * pre;
                    const int act = ((const volatile int*)active)[gr];
                    Hn[(size_t)gr * HDm + gc] = act ? av : Hs[(size_t)gr * HDm + gc];
                }
            }
            // fully-frozen tiles: Hn already holds the frozen values from the
            // last computed step (select copied them), so no copy is needed.
        }
        grid.sync();

        // ---- P2: logits = Hn @ W_HL + BL  (skip fully-frozen row-tiles) ----
        {
            const int row0 = (bid >> 4) * 32, col0 = (bid & 15) * 64;
            __syncthreads();
            if (tid < 64) {
                int a = (tid < 32) ? ((const volatile int*)active)[row0 + tid] : 0;
                unsigned long long bl = __ballot(a != 0);
                if (tid == 0) s_any = (bl != 0ull);
            }
            __syncthreads();
            if (s_any) {
                f32x4 acc;
                int s, p;
                tile32_gemm_ks(Hn, row0, WHLThi, WHLTlo, col0, lds, acc, s, p);
                // deterministic pair-reduction: odd-half waves park in LDS
                const int lane = tid & 63;
                f32x4* red = (f32x4*)lds;                 // reuse A region (8 KB)
                __syncthreads();
                if (p == 1) red[s * 64 + lane] = acc;
                __syncthreads();
                if (p == 0) {
                    f32x4 o = red[s * 64 + lane];
                    const int gc = col0 + (s & 3) * 16 + (lane & 15);
                    if (gc < LD) {
                        const int gr0 = row0 + (s >> 2) * 16 + ((lane >> 4) << 2);
                        const float blv = BL[gc];
#pragma unroll
                        for (int r = 0; r < 4; ++r)
                            logits[(size_t)(gr0 + r) * LD + gc] = acc[r] + o[r] + blv;
                    }
                }
            }
        }
        grid.sync();

        // ---- P3: per-row certification (one wave per row, 4096 waves) ----
        {
            const int lane = tid & 63;
            const int wave = bid * 16 + (tid >> 6);
            if (wave < BN) {
                const int b = wave;
                if (((const volatile int*)active)[b]) {
                    const float* hn = Hn + (size_t)b * HDm;
                    const float* hs = Hs + (size_t)b * HDm;
                    float dh = 0.f;
                    for (int h = lane; h < HDm; h += 64)
                        dh = fmaxf(dh, fabsf(hn[h] - hs[h]));
#pragma unroll
                    for (int off = 1; off < 64; off <<= 1)
                        dh = fmaxf(dh, __shfl_xor(dh, off));
                    const float* lr = logits + (size_t)b * LD;
                    float m1 = -3.4e38f, m2 = -3.4e38f;
                    for (int j = lane; j < LD; j += 64) {
                        float v = lr[j];
                        if (v > m1) { m2 = m1; m1 = v; }
                        else m2 = fmaxf(m2, v);
                    }
#pragma unroll
                    for (int off = 1; off < 64; off <<= 1) {
                        float o1 = __shfl_xor(m1, off);
                        float o2 = __shfl_xor(m2, off);
                        if (o1 > m1) { m2 = fmaxf(m1, o2); m1 = o1; }
                        else m2 = fmaxf(m2, o1);
                    }
                    const bool newly = (m1 - m2) > gamma2 * dh;
                    if (newly) {
                        for (int j = lane; j < LD; j += 64) out[(size_t)b * LD + j] = lr[j];
                        if (lane == 0) active[b] = 0;
                    } else if (lane == 0) {
                        atomicAdd(&nact[t], 1);
                    }
                }
            }
        }
        grid.sync();
        const int remaining = ((const volatile int*)nact)[t];
        float* tmp = Hs; Hs = Hn; Hn = tmp;
        if (remaining == 0) break;
    }

    // ---- never-certified rows take last logits ----
    {
        const int lane = tid & 63;
        const int wave = bid * 16 + (tid >> 6);
        if (wave < BN && ((const volatile int*)active)[wave]) {
            const float* lr = logits + (size_t)wave * LD;
            for (int j = lane; j < LD; j += 64) out[(size_t)wave * LD + j] = lr[j];
        }
    }
}

// ---------------------------------------------------------------------------
extern "C" void kernel_launch(void* const* d_in, const int* in_sizes, int n_in,
                              void* d_out, int out_size, void* d_ws, size_t ws_size,
                              hipStream_t stream)
{
    const float* x   = (const float*)d_in[0];
    const float* RIH = (const float*)d_in[1];
    const float* RH  = (const float*)d_in[2];
    const float* RHL = (const float*)d_in[3];
    const float* BH  = (const float*)d_in[4];
    const float* BL  = (const float*)d_in[5];
    const float* MIH = (const float*)d_in[6];
    const float* MH  = (const float*)d_in[7];
    const float* MHL = (const float*)d_in[8];
    float* out = (float*)d_out;
    char* w = (char*)d_ws;

    unsigned short* WHThi = (unsigned short*)(w);                 //  8 MB
    unsigned short* WHTlo = (unsigned short*)(w + 8388608);       //  8 MB
    unsigned short* WXhi  = (unsigned short*)(w + 16777216);      //  4 MB
    unsigned short* WXlo  = (unsigned short*)(w + 20971520);      //  4 MB
    float* drive  = (float*)(w + 25165824);                       //  4 MB
    float* Ha     = (float*)(w + 29360128);                       //  4 MB
    float* Hb     = (float*)(w + 33554432);                       //  4 MB
    float* logits = (float*)(w + 37748736);                       //  2 MB
    float* scal   = (float*)(w + 39796736);
    int*   active = (int*)(w + 39796768);
    int*   nact   = (int*)(w + 39798816);

    k_init<<<2, 256, 0, stream>>>(active, nact, scal);
    k_colsum_wh<<<32, 1024, 0, stream>>>(RH, MH, scal);
    k_colsum_whl<<<16, 1024, 0, stream>>>(RHL, MHL, scal);
    k_scalars<<<1, 64, 0, stream>>>(scal);
    k_wsplit<<<512, 256, 0, stream>>>(RIH, MIH, WXhi, WXlo, ID, HDm, HDm, scal, -1);
    k_drive_mfma<<<256, 1024, 0, stream>>>(x, WXhi, WXlo, BH, drive);
    k_wsplit<<<1024, 256, 0, stream>>>(RH, MH, WHThi, WHTlo, HDm, HDm, HDm, scal, 2);
    k_wsplit<<<512, 256, 0, stream>>>(RHL, MHL, WXhi, WXlo, HDm, LD, 1024, scal, -1);
    hipMemsetAsync(Ha, 0, (size_t)BN * HDm * sizeof(float), stream);

    void* args[] = {(void*)&WHThi, (void*)&WHTlo, (void*)&WXhi, (void*)&WXlo,
                    (void*)&drive, (void*)&BL, (void*)&Ha, (void*)&Hb, (void*)&logits,
                    (void*)&active, (void*)&nact, (void*)&scal, (void*)&out};
    hipLaunchCooperativeKernel(reinterpret_cast<void*>(k_crp_loop),
                               dim3(256), dim3(1024), args, 0, stream);
}